// Round 11
// baseline (85.380 us; speedup 1.0000x reference)
//
#include <hip/hip_runtime.h>

// RotMat forward: 511 rounds of 256 disjoint Givens rotations on rows of a
// [512, 1024] fp32 matrix (round-robin tournament schedule).
//
// Position-space: position k pairs with 511-k; after each round a cyclic
// shift sigma (0 fixed, 1<-511, p<-p-1). After 511 rounds permutation = id.
//
// R9/R10: 2-ROUND COMPOSITE STEPS (sigma R' sigma R), 255 steps + 1 single
// round. Fixed 4-source pattern per slot:
//   F_k <- {L(k-2), H(k-2), L_k, H_k},  G_k <- {L_k, H_k, L(k+2), H(k+2)}
// (k+-2 via DPP wave shifts; lane0/63 source specials via DPP `old`; all
// coefficient specials baked into a 2MB precomputed table.)
// R10 fixes R9's single algebra bug: G_0 must use A_1 = c0*H0 + s0*L0
// (coeffs (S1*s0, +S1*c0, C1*s2, C1*c2)), not the generic A_{k+1} form.
// Also: pinned coeff buffers 4 -> 2 (64 VGPRs) to stay clear of the spill
// cliff (scratch traffic corrupts counted vmcnt -- R8's failure class).
// Feed = R6/R7-proven: global_load_lds -> 64KB LDS dbuf, counted vmcnt(8),
// asm-pinned ds_read_b128 + counted lgkmcnt (<=8 waits, <=16 outstanding).

#define N_COLS   1024
#define PAIRS    256

typedef __attribute__((ext_vector_type(4))) float f32x4;

// ---- trig helper: signed (c, s) for round r, pair k ------------------------
__device__ __forceinline__ float2 cs_of(const float* __restrict__ th, int r, int k) {
    int pu = (k == 0) ? 0 : ((k - 1 - r + 1022) % 511) + 1;
    int pv = ((510 - k - r + 1022) % 511) + 1;
    int i = min(pu, pv), j = max(pu, pv);
    int t = i * 511 - (i * (i - 1)) / 2 + (j - i - 1);
    float s, c;
    sincosf(th[t], &s, &c);
    return make_float2(c, (pu < pv) ? s : -s);
}

// ---- setup 1: composite coefficients for steps b=0..254 (rounds 2b,2b+1) --
// Table (f32x4 units): step b, slot j (0..3 = lo m, 4..7 = hi m), lane l:
// idx = b*512 + j*64 + l.
__global__ __launch_bounds__(256) void setup_steps(const float* __restrict__ thetas,
                                                   float4* __restrict__ out4) {
    const int b = blockIdx.x;      // 0..254
    const int k = threadIdx.x;     // 0..255 (output pair index)
    const int r = 2 * b, rp = 2 * b + 1;

    float4 L, H;
    if (k == 0) {
        float2 c0 = cs_of(thetas, r, 0), c1 = cs_of(thetas, r, 1), C0 = cs_of(thetas, rp, 0);
        L = make_float4(C0.x * c0.x, -C0.x * c0.y, -C0.y * c1.y, -C0.y * c1.x);
    } else if (k == 1) {
        float2 c0 = cs_of(thetas, r, 0), c1 = cs_of(thetas, r, 1), C0 = cs_of(thetas, rp, 0);
        L = make_float4(C0.y * c0.x, -C0.y * c0.y, C0.x * c1.y, C0.x * c1.x);
    } else if (k == 2) {
        float2 c0 = cs_of(thetas, r, 0), c2 = cs_of(thetas, r, 2), C1 = cs_of(thetas, rp, 1);
        L = make_float4(C1.x * c0.y, C1.x * c0.x, -C1.y * c2.y, -C1.y * c2.x);
    } else {
        float2 ca = cs_of(thetas, r, k - 2), cb = cs_of(thetas, r, k), Cp = cs_of(thetas, rp, k - 1);
        L = make_float4(Cp.x * ca.x, -Cp.x * ca.y, -Cp.y * cb.y, -Cp.y * cb.x);
    }
    if (k == 0) {
        // G_0 = C_1 B_1 + S_1 A_1 with A_1 = c0*H0 + s0*L0 (NOT generic):
        // coeffs over (L0, H0, L2, H2) = (S1*s0, S1*c0, C1*s2, C1*c2).
        float2 cb = cs_of(thetas, r, 0), cc = cs_of(thetas, r, 2), Cq = cs_of(thetas, rp, 1);
        H = make_float4(Cq.y * cb.y, Cq.y * cb.x, Cq.x * cc.y, Cq.x * cc.x);
    } else if (k <= 253) {
        float2 cb = cs_of(thetas, r, k), cc = cs_of(thetas, r, k + 2), Cq = cs_of(thetas, rp, k + 1);
        H = make_float4(Cq.y * cb.x, -Cq.y * cb.y, Cq.x * cc.y, Cq.x * cc.x);
    } else if (k == 254) {
        float2 cb = cs_of(thetas, r, 254), cc = cs_of(thetas, r, 255), Cq = cs_of(thetas, rp, 255);
        H = make_float4(Cq.y * cb.x, -Cq.y * cb.y, Cq.x * cc.x, -Cq.x * cc.y);
    } else {  // k == 255
        float2 ca = cs_of(thetas, r, 254), cb = cs_of(thetas, r, 255), Cq = cs_of(thetas, rp, 255);
        H = make_float4(-Cq.y * cb.x, Cq.y * cb.y, Cq.x * ca.x, -Cq.x * ca.y);
    }
    const int l = k >> 2, m = k & 3;
    out4[b * 512 + m * 64 + l]       = L;
    out4[b * 512 + (4 + m) * 64 + l] = H;
}

// ---- setup 2: plane-form (c,s) for the final single round 510 -------------
__global__ __launch_bounds__(256) void setup_last(const float* __restrict__ thetas,
                                                  float2* __restrict__ cs) {
    const int k = threadIdx.x;
    float2 v = cs_of(thetas, 510, k);
    int plane = (k >> 1) & 1, l = k >> 2, slot = k & 1;
    cs[262144 + plane * 128 + l * 2 + slot] = v;
}

// ---- DPP wave-shift helpers (OOB lane keeps `old`) -------------------------
__device__ __forceinline__ float dpp_shr1(float old, float src) {
    return __int_as_float(__builtin_amdgcn_update_dpp(
        __float_as_int(old), __float_as_int(src), 0x138, 0xF, 0xF, false));
}
__device__ __forceinline__ float dpp_shl1(float old, float src) {
    return __int_as_float(__builtin_amdgcn_update_dpp(
        __float_as_int(old), __float_as_int(src), 0x130, 0xF, 0xF, false));
}

__device__ __forceinline__ void glds16(const void* g, void* l) {
    __builtin_amdgcn_global_load_lds(
        (const __attribute__((address_space(1))) void*)g,
        (__attribute__((address_space(3))) void*)l, 16, 0, 0);
}

#define ROT(mi, C, S)                                   \
    {                                                   \
        float L_ = lo[mi], H_ = hi[mi];                 \
        lo[mi] = fmaf((C), L_, -(S) * H_);              \
        hi[mi] = fmaf((C), H_, (S) * L_);               \
    }

#define SHIFT()                                                   \
    {                                                             \
        float nlo0 = dpp_shr1(lo[0], lo[3]);                      \
        float nhi3 = dpp_shl1(lo[3], hi[0]);                      \
        float nlo1 = is0 ? hi[0] : lo[0];                         \
        lo[3] = lo[2]; lo[2] = lo[1]; lo[1] = nlo1; lo[0] = nlo0; \
        hi[0] = hi[1]; hi[1] = hi[2]; hi[2] = hi[3]; hi[3] = nhi3;\
    }

// One composite step from 8 coeff vecs (QL0..3 lo, QH0..3 hi).
#define STEP(QL0, QL1, QL2, QL3, QH0, QH1, QH2, QH3)                          \
    {                                                                         \
        float loH2 = dpp_shr1(lo[0], lo[2]);                                  \
        float loH3 = dpp_shr1(lo[0], lo[3]);                                  \
        float hiH2 = dpp_shr1(hi[0], hi[2]);                                  \
        float hiH3 = dpp_shr1(hi[0], hi[3]);                                  \
        float loL0 = dpp_shl1(lo[3], lo[0]);                                  \
        float loL1 = dpp_shl1(lo[2], lo[1]);                                  \
        float hiL0 = dpp_shl1(hi[3], hi[0]);                                  \
        float hiL1 = dpp_shl1(hi[2], hi[1]);                                  \
        float Cs = is0 ? lo[1] : lo[0];                                       \
        float Ds = is0 ? hi[1] : hi[0];                                       \
        float nl0 = (QL0).x * loH2  + (QL0).y * hiH2  + (QL0).z * Cs    + (QL0).w * Ds;    \
        float nl1 = (QL1).x * loH3  + (QL1).y * hiH3  + (QL1).z * lo[1] + (QL1).w * hi[1]; \
        float nl2 = (QL2).x * lo[0] + (QL2).y * hi[0] + (QL2).z * lo[2] + (QL2).w * hi[2]; \
        float nl3 = (QL3).x * lo[1] + (QL3).y * hi[1] + (QL3).z * lo[3] + (QL3).w * hi[3]; \
        float nh0 = (QH0).x * lo[0] + (QH0).y * hi[0] + (QH0).z * lo[2] + (QH0).w * hi[2]; \
        float nh1 = (QH1).x * lo[1] + (QH1).y * hi[1] + (QH1).z * lo[3] + (QH1).w * hi[3]; \
        float nh2 = (QH2).x * lo[2] + (QH2).y * hi[2] + (QH2).z * loL0  + (QH2).w * hiL0;  \
        float nh3 = (QH3).x * lo[3] + (QH3).y * hi[3] + (QH3).z * loL1  + (QH3).w * hiL1;  \
        lo[0] = nl0; lo[1] = nl1; lo[2] = nl2; lo[3] = nl3;                   \
        hi[0] = nh0; hi[1] = nh1; hi[2] = nh2; hi[3] = nh3;                   \
    }

// Inline-asm ds_read_b128 (pinned, volatile; R6/R7-proven).
#define DSR(dst, imm)                                          \
    asm volatile("ds_read_b128 %0, %1 offset:%c2"              \
                 : "=v"(dst) : "v"(lds_addr), "i"(imm))

#define WAITL(n)                                                   \
    asm volatile("s_waitcnt lgkmcnt(" #n ")" ::: "memory");        \
    __builtin_amdgcn_sched_barrier(0)

// Issue 8 ds_reads for step st of chunk at BOFF into buffer s (a or b).
#define DS8(BOFF, st, s)                                                      \
    DSR(P##s##0, (BOFF) + (st)*8192 + 0 * 1024);                              \
    DSR(P##s##1, (BOFF) + (st)*8192 + 1 * 1024);                              \
    DSR(P##s##2, (BOFF) + (st)*8192 + 2 * 1024);                              \
    DSR(P##s##3, (BOFF) + (st)*8192 + 3 * 1024);                              \
    DSR(P##s##4, (BOFF) + (st)*8192 + 4 * 1024);                              \
    DSR(P##s##5, (BOFF) + (st)*8192 + 5 * 1024);                              \
    DSR(P##s##6, (BOFF) + (st)*8192 + 6 * 1024);                              \
    DSR(P##s##7, (BOFF) + (st)*8192 + 7 * 1024);

#define STEPS(s) STEP(P##s##0, P##s##1, P##s##2, P##s##3, P##s##4, P##s##5, P##s##6, P##s##7)

// Full chunk: 4 steps, 2 pinned buffers (64 VGPR), <=16 DS outstanding,
// waits at 8 (1-step lookahead covers LDS latency).
#define CBODY_FULL(BOFF)                                                      \
    {                                                                         \
        f32x4 Pa0, Pa1, Pa2, Pa3, Pa4, Pa5, Pa6, Pa7;                         \
        f32x4 Pb0, Pb1, Pb2, Pb3, Pb4, Pb5, Pb6, Pb7;                         \
        DS8(BOFF, 0, a)                                                       \
        DS8(BOFF, 1, b)                                                       \
        WAITL(8);  STEPS(a)                                                   \
        DS8(BOFF, 2, a)                                                       \
        WAITL(8);  STEPS(b)                                                   \
        DS8(BOFF, 3, b)                                                       \
        WAITL(8);  STEPS(a)                                                   \
        WAITL(0);  STEPS(b)                                                   \
    }

// Tail chunk: 3 real steps (pad step never read).
#define CBODY_TAIL(BOFF)                                                      \
    {                                                                         \
        f32x4 Pa0, Pa1, Pa2, Pa3, Pa4, Pa5, Pa6, Pa7;                         \
        f32x4 Pb0, Pb1, Pb2, Pb3, Pb4, Pb5, Pb6, Pb7;                         \
        DS8(BOFF, 0, a)                                                       \
        DS8(BOFF, 1, b)                                                       \
        WAITL(8);  STEPS(a)                                                   \
        DS8(BOFF, 2, a)                                                       \
        WAITL(8);  STEPS(b)                                                   \
        WAITL(0);  STEPS(a)                                                   \
    }

// Stage chunk cix (32KB: 4 steps) into buffer bix; wave covers its 8KB.
#define STAGE(cix, bix)                                              \
    {                                                                \
        const char* g_ = gsrc + (size_t)(cix)*32768;                 \
        char* l_ = lb + (bix)*32768;                                 \
        _Pragma("unroll")                                            \
        for (int j = 0; j < 8; ++j)                                  \
            glds16(g_ + j * 1024, l_ + j * 1024);                    \
    }

#define WAITV(n) asm volatile("s_waitcnt vmcnt(" #n ")" ::: "memory")
#define BAR()                               \
    __builtin_amdgcn_s_barrier();           \
    __builtin_amdgcn_sched_barrier(0)

template <bool TAB>
__global__ __launch_bounds__(256, 1) void rotmat_main(const float* __restrict__ x,
                                                      const float* __restrict__ thetas,
                                                      const float2* __restrict__ cs,
                                                      float* __restrict__ out) {
    __shared__ f32x4 tab[2][4][8][64];  // [buf][step][slot][lane] = 64KB

    const int lane = threadIdx.x & 63;
    const int wave = threadIdx.x >> 6;
    const int col  = (blockIdx.x << 2) + wave;  // one column per wave
    const int k0   = lane << 2;                 // first pair index of this lane
    const bool is0 = (lane == 0);

    float lo[4], hi[4];
#pragma unroll
    for (int m = 0; m < 4; ++m) {
        lo[m] = x[(k0 + m) * N_COLS + col];
        hi[m] = x[(511 - k0 - m) * N_COLS + col];
    }

    if constexpr (TAB) {
        // Final-round coeffs (2KB at f32x4 idx 131072), loaded early.
        const float4* T4g = reinterpret_cast<const float4*>(cs);
        float4 cL0 = T4g[131072 + lane];
        float4 cL1 = T4g[131072 + 64 + lane];

        const char* gsrc = (const char*)cs + (size_t)wave * 8192 + (size_t)lane * 16;
        char* lb = (char*)(&tab[0][0][0][0]) + wave * 8192;
        unsigned lds_addr;
        {
            auto p3 = (__attribute__((address_space(3))) char*)(&tab[0][0][0][0]);
            lds_addr = (unsigned)(size_t)p3 + (unsigned)(lane * 16);
        }

        // Prologue: stage chunks 0,1 (8 loads each/wave); wait chunk 0; sync.
        STAGE(0, 0)
        STAGE(1, 1)
        WAITV(8);
        BAR();

        // 64 chunks x 4 steps (255 real steps + 1 pad step in chunk 63).
        for (int t2 = 0; t2 < 31; ++t2) {
            CBODY_FULL(0)
            BAR();
            STAGE(2 * t2 + 2, 0)
            WAITV(8);
            BAR();
            CBODY_FULL(32768)
            BAR();
            STAGE(2 * t2 + 3, 1)
            WAITV(8);
            BAR();
        }
        CBODY_FULL(0)        // chunk 62 (steps 248..251)
        WAITV(0);
        BAR();
        CBODY_TAIL(32768)    // chunk 63 (steps 252..254; pad skipped)

        // Final single round (510).
        ROT(0, cL0.x, cL0.y)
        ROT(1, cL0.z, cL0.w)
        ROT(2, cL1.x, cL1.y)
        ROT(3, cL1.z, cL1.w)
        SHIFT()
    } else {
        // Fallback: compute schedule + sincos inline (no workspace table).
        int pu[4], pv[4];
#pragma unroll
        for (int m = 0; m < 4; ++m) {
            pu[m] = (k0 + m == 0) ? 0 : (k0 + m);
            pv[m] = 511 - (k0 + m);
        }
        for (int r = 0; r < 511; ++r) {
#pragma unroll
            for (int m = 0; m < 4; ++m) {
                int i = min(pu[m], pv[m]), j = max(pu[m], pv[m]);
                int t = i * 511 - (i * (i - 1)) / 2 + (j - i - 1);
                float s, c;
                sincosf(thetas[t], &s, &c);
                float sp = (pu[m] < pv[m]) ? s : -s;
                ROT(m, c, sp)
            }
            SHIFT()
#pragma unroll
            for (int m = 0; m < 4; ++m) {
                pu[m] = (k0 + m == 0) ? 0 : ((pu[m] == 1) ? 511 : pu[m] - 1);
                pv[m] = (pv[m] == 1) ? 511 : pv[m] - 1;
            }
        }
    }

    // After 511 shifts the position->row permutation is identity.
#pragma unroll
    for (int m = 0; m < 4; ++m) {
        out[(k0 + m) * N_COLS + col]       = lo[m];
        out[(511 - k0 - m) * N_COLS + col] = hi[m];
    }
}

extern "C" void kernel_launch(void* const* d_in, const int* in_sizes, int n_in,
                              void* d_out, int out_size, void* d_ws, size_t ws_size,
                              hipStream_t stream) {
    const float* x  = (const float*)d_in[0];
    const float* th = (const float*)d_in[1];
    float* out      = (float*)d_out;

    // Table: 256 steps (255 real + 1 pad, 8KB each) + final-round 2KB.
    const size_t need = (size_t)256 * 8192 + 2048;  // 2,099,200 B
    if (ws_size >= need) {
        float4* t4 = (float4*)d_ws;
        setup_steps<<<255, 256, 0, stream>>>(th, t4);
        setup_last<<<1, 256, 0, stream>>>(th, (float2*)d_ws);
        rotmat_main<true><<<N_COLS / 4, 256, 0, stream>>>(x, th, (const float2*)d_ws, out);
    } else {
        rotmat_main<false><<<N_COLS / 4, 256, 0, stream>>>(x, th, nullptr, out);
    }
}

// Round 12
// 51.390 us; speedup vs baseline: 1.6614x; 1.6614x over previous
//
#include <hip/hip_runtime.h>

// RotMat forward: 511 rounds of 256 disjoint Givens rotations on rows of a
// [512, 1024] fp32 matrix (round-robin tournament schedule).
//
// Position-space: position k pairs with 511-k every round; between rounds a
// fixed cyclic shift. After 511 rounds the permutation is identity.
//
// Ladder: R0 177us. R1 75us. R3 60us (DPP shifts). R4-R7 ~50.5us (LDS staging
// + asm-pinned ds_read + counted lgkm). R10 85us REGRESSION (2-round
// composite: 4x coeff bytes + 2x VALU -- data volume is first-class; revert).
// R11: smooth rolling pipeline on R7's dataflow:
//  - per-round ds_read_b128 pair issued 4 rounds ahead (ring of 4 slots,
//    8 outstanding), gated by counted lgkmcnt(6) waits that REDEFINE the
//    consumed regs ("+v") -> dataflow ordering, no sched_barrier walls,
//    rounds can overlap. (lgkm-safe: no compiler DS/SMEM in loop; R8's
//    failure was vmcnt + hidden scratch, not this mechanism.)
//  - triple-buffered 16KB chunks, ONE barrier per chunk. Protocol: each wave
//    WAITV(0) (own stage of chunk c+1 landed) BEFORE the barrier; after the
//    barrier all waves' stages are visible and all reads of the new staging
//    target (chunk c-1's buffer) have retired.

#define N_COLS   1024
#define PAIRS    256

typedef __attribute__((ext_vector_type(4))) float f32x4;

// Table layout (plane form): float2 index = r*256 + plane*128 + lane*2 + slot
// where pair k -> plane=(k>>1)&1, lane=k>>2, slot=k&1. Round r at byte r*2048;
// lane's planeA f32x4 at +lane*16, planeB at +1024+lane*16. Conflict-free.
__global__ __launch_bounds__(256) void rotmat_setup(const float* __restrict__ thetas,
                                                    float2* __restrict__ cs) {
    const int r = blockIdx.x;   // 0..510
    const int k = threadIdx.x;  // 0..255 (pair index)
    int pu = (k == 0) ? 0 : ((k - 1 - r + 1022) % 511) + 1;
    int pv = ((510 - k - r + 1022) % 511) + 1;
    int i = min(pu, pv), j = max(pu, pv);
    int t = i * 511 - (i * (i - 1)) / 2 + (j - i - 1);
    float s, c;
    sincosf(thetas[t], &s, &c);
    float sp = (pu < pv) ? s : -s;
    int plane = (k >> 1) & 1, ln = k >> 2, slot = k & 1;
    cs[r * 256 + plane * 128 + ln * 2 + slot] = make_float2(c, sp);
}

// DPP wave-shift helpers (OOB lane keeps `old`).
__device__ __forceinline__ float dpp_shr1(float old, float src) {
    return __int_as_float(__builtin_amdgcn_update_dpp(
        __float_as_int(old), __float_as_int(src), 0x138, 0xF, 0xF, false));
}
__device__ __forceinline__ float dpp_shl1(float old, float src) {
    return __int_as_float(__builtin_amdgcn_update_dpp(
        __float_as_int(old), __float_as_int(src), 0x130, 0xF, 0xF, false));
}

__device__ __forceinline__ void glds16(const void* g, void* l) {
    __builtin_amdgcn_global_load_lds(
        (const __attribute__((address_space(1))) void*)g,
        (__attribute__((address_space(3))) void*)l, 16, 0, 0);
}

#define ROT(mi, C, S)                                   \
    {                                                   \
        float L_ = lo[mi], H_ = hi[mi];                 \
        lo[mi] = fmaf((C), L_, -(S) * H_);              \
        hi[mi] = fmaf((C), H_, (S) * L_);               \
    }

#define SHIFT()                                                   \
    {                                                             \
        float nlo0 = dpp_shr1(lo[0], lo[3]);                      \
        float nhi3 = dpp_shl1(lo[3], hi[0]);                      \
        float nlo1 = is0 ? hi[0] : lo[0];                         \
        lo[3] = lo[2]; lo[2] = lo[1]; lo[1] = nlo1; lo[0] = nlo0; \
        hi[0] = hi[1]; hi[1] = hi[2]; hi[2] = hi[3]; hi[3] = nhi3;\
    }

#define ROUND(AA, BB)            \
    ROT(0, (AA).x, (AA).y)       \
    ROT(1, (AA).z, (AA).w)       \
    ROT(2, (BB).x, (BB).y)       \
    ROT(3, (BB).z, (BB).w)       \
    SHIFT()

// Volatile pinned ds_read_b128 with register base + immediate offset.
#define DSRD(dst, addr, imm)                                   \
    asm volatile("ds_read_b128 %0, %1 offset:%c2"              \
                 : "=v"(dst) : "v"(addr), "i"(imm))

// Counted lgkm waits that redefine the covered regs: consumers are
// dataflow-ordered after the wait; no sched_barrier wall needed.
#define WL6(a, b) asm volatile("s_waitcnt lgkmcnt(6)" : "+v"(a), "+v"(b))
#define WL4(a, b) asm volatile("s_waitcnt lgkmcnt(4)" : "+v"(a), "+v"(b))
#define WL2(a, b) asm volatile("s_waitcnt lgkmcnt(2)" : "+v"(a), "+v"(b))

#define WAITV(n) asm volatile("s_waitcnt vmcnt(" #n ")" ::: "memory")
#define BAR()                               \
    __builtin_amdgcn_s_barrier();           \
    __builtin_amdgcn_sched_barrier(0)

// Stage chunk cix (16KB) into buffer bix; wave covers its 4KB (4 x 1KB).
#define STAGE(cix, bix)                                              \
    {                                                                \
        const char* g_ = gsrc + (size_t)(cix)*16384;                 \
        char* l_ = lb + (size_t)(bix)*16384;                         \
        _Pragma("unroll")                                            \
        for (int j = 0; j < 4; ++j)                                  \
            glds16(g_ + j * 1024, l_ + j * 1024);                    \
    }

// One full chunk: 8 rounds, rolling 4-round-ahead reads. Rounds 0..3 issue
// reads for rounds 4..7 (same chunk, ACUR); rounds 4..7 issue reads for the
// next chunk's rounds 0..3 (ANXT).
#define CHUNK8(ACUR, ANXT)                                                         \
    WL6(A0, B0); ROUND(A0, B0) DSRD(A0, ACUR, 4*2048); DSRD(B0, ACUR, 4*2048+1024);\
    WL6(A1, B1); ROUND(A1, B1) DSRD(A1, ACUR, 5*2048); DSRD(B1, ACUR, 5*2048+1024);\
    WL6(A2, B2); ROUND(A2, B2) DSRD(A2, ACUR, 6*2048); DSRD(B2, ACUR, 6*2048+1024);\
    WL6(A3, B3); ROUND(A3, B3) DSRD(A3, ACUR, 7*2048); DSRD(B3, ACUR, 7*2048+1024);\
    WL6(A0, B0); ROUND(A0, B0) DSRD(A0, ANXT, 0*2048); DSRD(B0, ANXT, 0*2048+1024);\
    WL6(A1, B1); ROUND(A1, B1) DSRD(A1, ANXT, 1*2048); DSRD(B1, ANXT, 1*2048+1024);\
    WL6(A2, B2); ROUND(A2, B2) DSRD(A2, ANXT, 2*2048); DSRD(B2, ANXT, 2*2048+1024);\
    WL6(A3, B3); ROUND(A3, B3) DSRD(A3, ANXT, 3*2048); DSRD(B3, ANXT, 3*2048+1024);

template <bool TAB>
__global__ __launch_bounds__(256, 1) void rotmat_main(const float* __restrict__ x,
                                                      const float* __restrict__ thetas,
                                                      const float2* __restrict__ cs,
                                                      float* __restrict__ out) {
    __shared__ f32x4 tab[3 * 1024];  // 3 buffers x 16KB = 48KB

    const int lane = threadIdx.x & 63;
    const int wave = threadIdx.x >> 6;
    const int col  = (blockIdx.x << 2) + wave;  // one column per wave
    const int k0   = lane << 2;                 // first pair index of this lane
    const bool is0 = (lane == 0);

    float lo[4], hi[4];
#pragma unroll
    for (int m = 0; m < 4; ++m) {
        lo[m] = x[(k0 + m) * N_COLS + col];
        hi[m] = x[(511 - k0 - m) * N_COLS + col];
    }

    if constexpr (TAB) {
        const char* gsrc = (const char*)cs + (size_t)wave * 4096 + (size_t)lane * 16;
        char* lb = (char*)(&tab[0]) + (size_t)wave * 4096;
        unsigned ldsLane;
        {
            auto p3 = (__attribute__((address_space(3))) char*)(&tab[0]);
            ldsLane = (unsigned)(size_t)p3 + (unsigned)(lane * 16);
        }

        f32x4 A0, A1, A2, A3, B0, B1, B2, B3;  // ring: slot = round mod 4

        // Prologue: stage chunks 0,1; own chunk-0 loads landed; sync; then
        // pre-issue reads for chunk 0 rounds 0..3.
        STAGE(0, 0)
        STAGE(1, 1)
        WAITV(4);
        BAR();
        {
            unsigned a0 = ldsLane;  // buffer 0 base
            DSRD(A0, a0, 0 * 2048); DSRD(B0, a0, 0 * 2048 + 1024);
            DSRD(A1, a0, 1 * 2048); DSRD(B1, a0, 1 * 2048 + 1024);
            DSRD(A2, a0, 2 * 2048); DSRD(B2, a0, 2 * 2048 + 1024);
            DSRD(A3, a0, 3 * 2048); DSRD(B3, a0, 3 * 2048 + 1024);
        }

        // Chunks 0..61 (rounds 0..495), staging c+2 each.
        int bufCur = 0, bufNxt = 1, bufStg = 2;
        for (int c = 0; c < 62; ++c) {
            WAITV(0);   // own stage(c+1) landed (issued at top of c-1)
            BAR();      // all waves: stages visible; old-buffer reads retired
            STAGE(c + 2, bufStg)
            unsigned aCur = ldsLane + (unsigned)bufCur * 16384u;
            unsigned aNxt = ldsLane + (unsigned)bufNxt * 16384u;
            CHUNK8(aCur, aNxt)
            int t_ = bufCur; bufCur = bufNxt; bufNxt = bufStg; bufStg = t_;
        }

        // Chunk 62 (rounds 496..503): no staging (chunk 63 staged at c=61).
        {
            WAITV(0);   // stage(63) landed
            BAR();
            unsigned aCur = ldsLane + (unsigned)bufCur * 16384u;
            unsigned aNxt = ldsLane + (unsigned)bufNxt * 16384u;
            CHUNK8(aCur, aNxt)
            int t_ = bufCur; bufCur = bufNxt; bufNxt = bufStg; bufStg = t_;
        }

        // Chunk 63 tail: rounds 504..510 (7 real; round 511 is pad).
        {
            unsigned aCur = ldsLane + (unsigned)bufCur * 16384u;
            WL6(A0, B0); ROUND(A0, B0)
            DSRD(A0, aCur, 4 * 2048); DSRD(B0, aCur, 4 * 2048 + 1024);
            WL6(A1, B1); ROUND(A1, B1)
            DSRD(A1, aCur, 5 * 2048); DSRD(B1, aCur, 5 * 2048 + 1024);
            WL6(A2, B2); ROUND(A2, B2)
            DSRD(A2, aCur, 6 * 2048); DSRD(B2, aCur, 6 * 2048 + 1024);
            WL6(A3, B3); ROUND(A3, B3)
            DSRD(A3, aCur, 7 * 2048); DSRD(B3, aCur, 7 * 2048 + 1024);
            WL6(A0, B0); ROUND(A0, B0)   // round 508
            WL4(A1, B1); ROUND(A1, B1)   // round 509
            WL2(A2, B2); ROUND(A2, B2)   // round 510
            // Drain pad reads (A3,B3 dead) before epilogue register reuse.
            asm volatile("s_waitcnt lgkmcnt(0)" ::: "memory");
        }
    } else {
        // Fallback: compute schedule + sincos inline (no workspace table).
        int pu[4], pv[4];
#pragma unroll
        for (int m = 0; m < 4; ++m) {
            pu[m] = (k0 + m == 0) ? 0 : (k0 + m);
            pv[m] = 511 - (k0 + m);
        }
        for (int r = 0; r < 511; ++r) {
#pragma unroll
            for (int m = 0; m < 4; ++m) {
                int i = min(pu[m], pv[m]), j = max(pu[m], pv[m]);
                int t = i * 511 - (i * (i - 1)) / 2 + (j - i - 1);
                float s, c;
                sincosf(thetas[t], &s, &c);
                float sp = (pu[m] < pv[m]) ? s : -s;
                ROT(m, c, sp)
            }
            SHIFT()
#pragma unroll
            for (int m = 0; m < 4; ++m) {
                pu[m] = (k0 + m == 0) ? 0 : ((pu[m] == 1) ? 511 : pu[m] - 1);
                pv[m] = (pv[m] == 1) ? 511 : pv[m] - 1;
            }
        }
    }

    // After 511 shifts the position->row permutation is identity.
#pragma unroll
    for (int m = 0; m < 4; ++m) {
        out[(k0 + m) * N_COLS + col]       = lo[m];
        out[(511 - k0 - m) * N_COLS + col] = hi[m];
    }
}

extern "C" void kernel_launch(void* const* d_in, const int* in_sizes, int n_in,
                              void* d_out, int out_size, void* d_ws, size_t ws_size,
                              hipStream_t stream) {
    const float* x  = (const float*)d_in[0];
    const float* th = (const float*)d_in[1];
    float* out      = (float*)d_out;

    // Table: 512 rounds padded (chunk 63 includes pad round 511; staged but
    // its data is never consumed).
    const size_t need = (size_t)512 * PAIRS * sizeof(float2);  // 1 MiB
    if (ws_size >= need) {
        float2* cs = (float2*)d_ws;
        rotmat_setup<<<511, PAIRS, 0, stream>>>(th, cs);
        rotmat_main<true><<<N_COLS / 4, 256, 0, stream>>>(x, th, cs, out);
    } else {
        rotmat_main<false><<<N_COLS / 4, 256, 0, stream>>>(x, th, nullptr, out);
    }
}

// Round 13
// 49.306 us; speedup vs baseline: 1.7317x; 1.0423x over previous
//
#include <hip/hip_runtime.h>

// RotMat forward: 511 rounds of 256 disjoint Givens rotations on rows of a
// [512, 1024] fp32 matrix (round-robin tournament schedule).
//
// Position-space: position k pairs with 511-k every round; between rounds a
// fixed cyclic shift. After 511 rounds the permutation is identity.
//
// Ladder: R0 177us. R1 75us. R3 60us (DPP). R4-R7 ~50.5us (LDS + asm-pinned
// ds_read + counted lgkm). R10 85us regression (composite: data volume).
// R11 51.4us (rolling pipeline, 1 barrier/chunk) -- null. Conclusion: a
// ~170cy/round BASE cost survives every feed structure; even pure-register
// rounds (R6) run ~190cy. R12 attacks the round body's in-order issue stream:
//  - ROT(3), ROT(0) (DPP-source producers) first; both DPPs issued
//    immediately after; rename-fed ROT(1)/ROT(2)+cndmask fill the DPP shadow.
//  - pure-SSA round body (explicit temporaries, no register rotation movs).
//  - 16-round chunks (3 x 32KB LDS buffers), halving barrier count to 32.
//  - tail never touches the pad round.
// Feed protocol unchanged from R11 (proven): glds16 staging, WAITV(0)+BAR
// per chunk, rolling 4-round-ahead asm ds_read_b128 with counted lgkm waits
// that redefine ("+v") the consumed regs.

#define N_COLS   1024
#define PAIRS    256

typedef __attribute__((ext_vector_type(4))) float f32x4;

// Table layout (plane form): float2 index = r*256 + plane*128 + lane*2 + slot
// where pair k -> plane=(k>>1)&1, lane=k>>2, slot=k&1. Round r at byte r*2048;
// lane's planeA f32x4 at +lane*16, planeB at +1024+lane*16. Conflict-free.
__global__ __launch_bounds__(256) void rotmat_setup(const float* __restrict__ thetas,
                                                    float2* __restrict__ cs) {
    const int r = blockIdx.x;   // 0..510
    const int k = threadIdx.x;  // 0..255 (pair index)
    int pu = (k == 0) ? 0 : ((k - 1 - r + 1022) % 511) + 1;
    int pv = ((510 - k - r + 1022) % 511) + 1;
    int i = min(pu, pv), j = max(pu, pv);
    int t = i * 511 - (i * (i - 1)) / 2 + (j - i - 1);
    float s, c;
    sincosf(thetas[t], &s, &c);
    float sp = (pu < pv) ? s : -s;
    int plane = (k >> 1) & 1, ln = k >> 2, slot = k & 1;
    cs[r * 256 + plane * 128 + ln * 2 + slot] = make_float2(c, sp);
}

// DPP wave-shift helpers (OOB lane keeps `old`).
__device__ __forceinline__ float dpp_shr1(float old, float src) {
    return __int_as_float(__builtin_amdgcn_update_dpp(
        __float_as_int(old), __float_as_int(src), 0x138, 0xF, 0xF, false));
}
__device__ __forceinline__ float dpp_shl1(float old, float src) {
    return __int_as_float(__builtin_amdgcn_update_dpp(
        __float_as_int(old), __float_as_int(src), 0x130, 0xF, 0xF, false));
}

__device__ __forceinline__ void glds16(const void* g, void* l) {
    __builtin_amdgcn_global_load_lds(
        (const __attribute__((address_space(1))) void*)g,
        (__attribute__((address_space(3))) void*)l, 16, 0, 0);
}

// One round, DPP-early schedule, pure SSA. Coeffs: AA=(c0,s0,c1,s1) pairs
// {4l,4l+1}, BB=(c2,s2,c3,s3) pairs {4l+2,4l+3}. Equivalent op-for-op to the
// R11 ROUND+SHIFT (same fmaf/mul trees) -- only the issue order changed.
#define ROUND(AA, BB)                                              \
    {                                                              \
        float t3 = (BB).w * hi[3], u3 = (BB).w * lo[3];            \
        float l3 = fmaf((BB).z, lo[3], -t3);                       \
        float h3 = fmaf((BB).z, hi[3], u3);                        \
        float t0 = (AA).y * hi[0], u0 = (AA).y * lo[0];            \
        float l0 = fmaf((AA).x, lo[0], -t0);                       \
        float h0 = fmaf((AA).x, hi[0], u0);                        \
        float nlo0 = dpp_shr1(l0, l3);                             \
        float nhi3 = dpp_shl1(l3, h0);                             \
        float t1 = (AA).w * hi[1], u1 = (AA).w * lo[1];            \
        float l1 = fmaf((AA).z, lo[1], -t1);                       \
        float h1 = fmaf((AA).z, hi[1], u1);                        \
        float t2 = (BB).y * hi[2], u2 = (BB).y * lo[2];            \
        float l2 = fmaf((BB).x, lo[2], -t2);                       \
        float h2 = fmaf((BB).x, hi[2], u2);                        \
        float nlo1 = is0 ? h0 : l0;                                \
        lo[0] = nlo0; lo[1] = nlo1; lo[2] = l1; lo[3] = l2;        \
        hi[0] = h1; hi[1] = h2; hi[2] = h3; hi[3] = nhi3;          \
    }

// Volatile pinned ds_read_b128 with register base + immediate offset.
#define DSRD(dst, addr, imm)                                   \
    asm volatile("ds_read_b128 %0, %1 offset:%c2"              \
                 : "=v"(dst) : "v"(addr), "i"(imm))

// Counted lgkm waits that redefine the covered regs (dataflow ordering).
#define WL6(a, b) asm volatile("s_waitcnt lgkmcnt(6)" : "+v"(a), "+v"(b))
#define WL4(a, b) asm volatile("s_waitcnt lgkmcnt(4)" : "+v"(a), "+v"(b))
#define WL2(a, b) asm volatile("s_waitcnt lgkmcnt(2)" : "+v"(a), "+v"(b))
#define WL0(a, b) asm volatile("s_waitcnt lgkmcnt(0)" : "+v"(a), "+v"(b))

#define WAITV(n) asm volatile("s_waitcnt vmcnt(" #n ")" ::: "memory")
#define BAR()                               \
    __builtin_amdgcn_s_barrier();           \
    __builtin_amdgcn_sched_barrier(0)

// Stage chunk cix (32KB = 16 rounds) into buffer bix; wave covers its 8KB.
#define STAGE(cix, bix)                                              \
    {                                                                \
        const char* g_ = gsrc + (size_t)(cix)*32768;                 \
        char* l_ = lb + (size_t)(bix)*32768;                         \
        _Pragma("unroll")                                            \
        for (int j = 0; j < 8; ++j)                                  \
            glds16(g_ + j * 1024, l_ + j * 1024);                    \
    }

// 16 rounds, rolling 4-round-ahead reads. Rounds 0..11 read same-chunk
// rounds 4..15 (ACUR); rounds 12..15 read next chunk's rounds 0..3 (ANXT).
#define CHUNK16(ACUR, ANXT)                                                          \
    WL6(A0, B0); ROUND(A0, B0) DSRD(A0, ACUR,  4*2048); DSRD(B0, ACUR,  4*2048+1024);\
    WL6(A1, B1); ROUND(A1, B1) DSRD(A1, ACUR,  5*2048); DSRD(B1, ACUR,  5*2048+1024);\
    WL6(A2, B2); ROUND(A2, B2) DSRD(A2, ACUR,  6*2048); DSRD(B2, ACUR,  6*2048+1024);\
    WL6(A3, B3); ROUND(A3, B3) DSRD(A3, ACUR,  7*2048); DSRD(B3, ACUR,  7*2048+1024);\
    WL6(A0, B0); ROUND(A0, B0) DSRD(A0, ACUR,  8*2048); DSRD(B0, ACUR,  8*2048+1024);\
    WL6(A1, B1); ROUND(A1, B1) DSRD(A1, ACUR,  9*2048); DSRD(B1, ACUR,  9*2048+1024);\
    WL6(A2, B2); ROUND(A2, B2) DSRD(A2, ACUR, 10*2048); DSRD(B2, ACUR, 10*2048+1024);\
    WL6(A3, B3); ROUND(A3, B3) DSRD(A3, ACUR, 11*2048); DSRD(B3, ACUR, 11*2048+1024);\
    WL6(A0, B0); ROUND(A0, B0) DSRD(A0, ACUR, 12*2048); DSRD(B0, ACUR, 12*2048+1024);\
    WL6(A1, B1); ROUND(A1, B1) DSRD(A1, ACUR, 13*2048); DSRD(B1, ACUR, 13*2048+1024);\
    WL6(A2, B2); ROUND(A2, B2) DSRD(A2, ACUR, 14*2048); DSRD(B2, ACUR, 14*2048+1024);\
    WL6(A3, B3); ROUND(A3, B3) DSRD(A3, ACUR, 15*2048); DSRD(B3, ACUR, 15*2048+1024);\
    WL6(A0, B0); ROUND(A0, B0) DSRD(A0, ANXT,  0*2048); DSRD(B0, ANXT,  0*2048+1024);\
    WL6(A1, B1); ROUND(A1, B1) DSRD(A1, ANXT,  1*2048); DSRD(B1, ANXT,  1*2048+1024);\
    WL6(A2, B2); ROUND(A2, B2) DSRD(A2, ANXT,  2*2048); DSRD(B2, ANXT,  2*2048+1024);\
    WL6(A3, B3); ROUND(A3, B3) DSRD(A3, ANXT,  3*2048); DSRD(B3, ANXT,  3*2048+1024);

template <bool TAB>
__global__ __launch_bounds__(256, 1) void rotmat_main(const float* __restrict__ x,
                                                      const float* __restrict__ thetas,
                                                      const float2* __restrict__ cs,
                                                      float* __restrict__ out) {
    __shared__ f32x4 tab[3 * 2048];  // 3 buffers x 32KB = 96KB

    const int lane = threadIdx.x & 63;
    const int wave = threadIdx.x >> 6;
    const int col  = (blockIdx.x << 2) + wave;  // one column per wave
    const int k0   = lane << 2;                 // first pair index of this lane
    const bool is0 = (lane == 0);

    float lo[4], hi[4];
#pragma unroll
    for (int m = 0; m < 4; ++m) {
        lo[m] = x[(k0 + m) * N_COLS + col];
        hi[m] = x[(511 - k0 - m) * N_COLS + col];
    }

    if constexpr (TAB) {
        const char* gsrc = (const char*)cs + (size_t)wave * 8192 + (size_t)lane * 16;
        char* lb = (char*)(&tab[0]) + (size_t)wave * 8192;
        unsigned ldsLane;
        {
            auto p3 = (__attribute__((address_space(3))) char*)(&tab[0]);
            ldsLane = (unsigned)(size_t)p3 + (unsigned)(lane * 16);
        }

        f32x4 A0, A1, A2, A3, B0, B1, B2, B3;  // ring: slot = round mod 4

        // Prologue: stage chunks 0,1; both landed; sync; pre-issue reads for
        // chunk 0 rounds 0..3.
        STAGE(0, 0)
        STAGE(1, 1)
        WAITV(0);
        BAR();
        {
            unsigned a0 = ldsLane;  // buffer 0 base
            DSRD(A0, a0, 0 * 2048); DSRD(B0, a0, 0 * 2048 + 1024);
            DSRD(A1, a0, 1 * 2048); DSRD(B1, a0, 1 * 2048 + 1024);
            DSRD(A2, a0, 2 * 2048); DSRD(B2, a0, 2 * 2048 + 1024);
            DSRD(A3, a0, 3 * 2048); DSRD(B3, a0, 3 * 2048 + 1024);
        }

        // Chunks 0..29 (rounds 0..479), staging chunk c+2 each.
        int bufCur = 0, bufNxt = 1, bufStg = 2;
        for (int c = 0; c < 30; ++c) {
            WAITV(0);   // own stage(c+1) landed (issued at top of c-1)
            BAR();      // all waves: stages visible; old-buffer reads retired
            STAGE(c + 2, bufStg)
            unsigned aCur = ldsLane + (unsigned)bufCur * 32768u;
            unsigned aNxt = ldsLane + (unsigned)bufNxt * 32768u;
            CHUNK16(aCur, aNxt)
            int t_ = bufCur; bufCur = bufNxt; bufNxt = bufStg; bufStg = t_;
        }

        // Chunk 30 (rounds 480..495): no staging (chunk 31 staged at c=29).
        {
            WAITV(0);   // stage(31) landed
            BAR();
            unsigned aCur = ldsLane + (unsigned)bufCur * 32768u;
            unsigned aNxt = ldsLane + (unsigned)bufNxt * 32768u;
            CHUNK16(aCur, aNxt)
            int t_ = bufCur; bufCur = bufNxt; bufNxt = bufStg; bufStg = t_;
        }

        // Chunk 31 tail: rounds 496..510 (15 real; pad round 511 never read).
        // Rounds 0..10 read +4 (rounds 4..14); rounds 11..14 drain the ring.
        {
            unsigned aCur = ldsLane + (unsigned)bufCur * 32768u;
            WL6(A0, B0); ROUND(A0, B0)
            DSRD(A0, aCur, 4 * 2048); DSRD(B0, aCur, 4 * 2048 + 1024);
            WL6(A1, B1); ROUND(A1, B1)
            DSRD(A1, aCur, 5 * 2048); DSRD(B1, aCur, 5 * 2048 + 1024);
            WL6(A2, B2); ROUND(A2, B2)
            DSRD(A2, aCur, 6 * 2048); DSRD(B2, aCur, 6 * 2048 + 1024);
            WL6(A3, B3); ROUND(A3, B3)
            DSRD(A3, aCur, 7 * 2048); DSRD(B3, aCur, 7 * 2048 + 1024);
            WL6(A0, B0); ROUND(A0, B0)
            DSRD(A0, aCur, 8 * 2048); DSRD(B0, aCur, 8 * 2048 + 1024);
            WL6(A1, B1); ROUND(A1, B1)
            DSRD(A1, aCur, 9 * 2048); DSRD(B1, aCur, 9 * 2048 + 1024);
            WL6(A2, B2); ROUND(A2, B2)
            DSRD(A2, aCur, 10 * 2048); DSRD(B2, aCur, 10 * 2048 + 1024);
            WL6(A3, B3); ROUND(A3, B3)
            DSRD(A3, aCur, 11 * 2048); DSRD(B3, aCur, 11 * 2048 + 1024);
            WL6(A0, B0); ROUND(A0, B0)
            DSRD(A0, aCur, 12 * 2048); DSRD(B0, aCur, 12 * 2048 + 1024);
            WL6(A1, B1); ROUND(A1, B1)
            DSRD(A1, aCur, 13 * 2048); DSRD(B1, aCur, 13 * 2048 + 1024);
            WL6(A2, B2); ROUND(A2, B2)
            DSRD(A2, aCur, 14 * 2048); DSRD(B2, aCur, 14 * 2048 + 1024);
            WL6(A3, B3); ROUND(A3, B3)   // round 507 (no more issues)
            WL4(A0, B0); ROUND(A0, B0)   // round 508
            WL2(A1, B1); ROUND(A1, B1)   // round 509
            WL0(A2, B2); ROUND(A2, B2)   // round 510; ring drained
        }
    } else {
        // Fallback: compute schedule + sincos inline (no workspace table).
        int pu[4], pv[4];
#pragma unroll
        for (int m = 0; m < 4; ++m) {
            pu[m] = (k0 + m == 0) ? 0 : (k0 + m);
            pv[m] = 511 - (k0 + m);
        }
        for (int r = 0; r < 511; ++r) {
            f32x4 AA, BB;
#pragma unroll
            for (int m = 0; m < 4; ++m) {
                int i = min(pu[m], pv[m]), j = max(pu[m], pv[m]);
                int t = i * 511 - (i * (i - 1)) / 2 + (j - i - 1);
                float s, c;
                sincosf(thetas[t], &s, &c);
                float sp = (pu[m] < pv[m]) ? s : -s;
                if (m == 0) { AA.x = c; AA.y = sp; }
                if (m == 1) { AA.z = c; AA.w = sp; }
                if (m == 2) { BB.x = c; BB.y = sp; }
                if (m == 3) { BB.z = c; BB.w = sp; }
            }
            ROUND(AA, BB)
#pragma unroll
            for (int m = 0; m < 4; ++m) {
                pu[m] = (k0 + m == 0) ? 0 : ((pu[m] == 1) ? 511 : pu[m] - 1);
                pv[m] = (pv[m] == 1) ? 511 : pv[m] - 1;
            }
        }
    }

    // After 511 shifts the position->row permutation is identity.
#pragma unroll
    for (int m = 0; m < 4; ++m) {
        out[(k0 + m) * N_COLS + col]       = lo[m];
        out[(511 - k0 - m) * N_COLS + col] = hi[m];
    }
}

extern "C" void kernel_launch(void* const* d_in, const int* in_sizes, int n_in,
                              void* d_out, int out_size, void* d_ws, size_t ws_size,
                              hipStream_t stream) {
    const float* x  = (const float*)d_in[0];
    const float* th = (const float*)d_in[1];
    float* out      = (float*)d_out;

    // Table: 512 rounds padded (chunk 31 stages pad round 511; never read).
    const size_t need = (size_t)512 * PAIRS * sizeof(float2);  // 1 MiB
    if (ws_size >= need) {
        float2* cs = (float2*)d_ws;
        rotmat_setup<<<511, PAIRS, 0, stream>>>(th, cs);
        rotmat_main<true><<<N_COLS / 4, 256, 0, stream>>>(x, th, cs, out);
    } else {
        rotmat_main<false><<<N_COLS / 4, 256, 0, stream>>>(x, th, nullptr, out);
    }
}

// Round 14
// 45.660 us; speedup vs baseline: 1.8699x; 1.0799x over previous
//
#include <hip/hip_runtime.h>
#include <hip/hip_fp16.h>

// RotMat forward: 511 rounds of 256 disjoint Givens rotations on rows of a
// [512, 1024] fp32 matrix (round-robin tournament schedule).
//
// Position-space: position k pairs with 511-k every round; between rounds a
// fixed cyclic shift. After 511 rounds the permutation is identity.
//
// Ladder: R0 177us. R1 75us. R3 60us (DPP). R4-R7 ~50.5us (LDS + pinned
// ds_read + counted lgkm). R10 85us regression (composite = 4x data volume).
// R11 51.4, R12 49.3 (schedule polish: null). Resource accounting: per CU the
// 4 waves move 8KB/round of f32 coeffs through the shared LDS pipe (~96cy) +
// staging (~24cy) while each SIMD issues ~70cy VALU; lockstep makes these ADD
// (~210cy/round measured). R13: HALVE the pipe demand -- coefficients stored
// as packed f16 (__half2 per pair): ONE ds_read_b128 per round per wave
// (16B/lane = 4 pairs), staging volume halved (512KB table), +8 v_cvt per
// round. Error: f16 entry err ~2.4e-4, 511-round random walk ~3.5e-2 absmax
// vs 9.25e-2 threshold. Skeleton = R12's proven protocol (glds16 triple
// buffer, WAITV(0)+BAR per 16-round chunk, pinned asm ds_read, counted lgkm
// "+v" waits -- now depth 4, lgkmcnt(3)).

#define N_COLS   1024
#define PAIRS    256

typedef __attribute__((ext_vector_type(4))) float f32x4;

// Table layout: round r occupies bytes [r*1024, r*1024+1024); pair k's packed
// (c,s) __half2 at byte r*1024 + k*4. Lane l reads one b128 at +l*16 covering
// its pairs 4l..4l+3. Stride-16B across lanes: conflict-free.
__global__ __launch_bounds__(256) void rotmat_setup(const float* __restrict__ thetas,
                                                    __half2* __restrict__ cs16) {
    const int r = blockIdx.x;   // 0..510
    const int k = threadIdx.x;  // 0..255 (pair index)
    int pu = (k == 0) ? 0 : ((k - 1 - r + 1022) % 511) + 1;
    int pv = ((510 - k - r + 1022) % 511) + 1;
    int i = min(pu, pv), j = max(pu, pv);
    int t = i * 511 - (i * (i - 1)) / 2 + (j - i - 1);
    float s, c;
    sincosf(thetas[t], &s, &c);
    float sp = (pu < pv) ? s : -s;
    cs16[r * 256 + k] = __floats2half2_rn(c, sp);
}

// DPP wave-shift helpers (OOB lane keeps `old`).
__device__ __forceinline__ float dpp_shr1(float old, float src) {
    return __int_as_float(__builtin_amdgcn_update_dpp(
        __float_as_int(old), __float_as_int(src), 0x138, 0xF, 0xF, false));
}
__device__ __forceinline__ float dpp_shl1(float old, float src) {
    return __int_as_float(__builtin_amdgcn_update_dpp(
        __float_as_int(old), __float_as_int(src), 0x130, 0xF, 0xF, false));
}

__device__ __forceinline__ void glds16(const void* g, void* l) {
    __builtin_amdgcn_global_load_lds(
        (const __attribute__((address_space(1))) void*)g,
        (__attribute__((address_space(3))) void*)l, 16, 0, 0);
}

__device__ __forceinline__ __half2 f2h2(float f) {
    union { float f; __half2 h; } u; u.f = f; return u.h;
}

// One round from one packed f32x4 (4 x __half2). DPP-early schedule (R12):
// ROT3 and ROT0 (DPP-source producers) first, DPPs immediately after,
// ROT1/ROT2 + cndmask fill the DPP shadow. Pure SSA.
#define ROUND(AA)                                                  \
    {                                                              \
        __half2 P0 = f2h2((AA).x), P3 = f2h2((AA).w);              \
        float c3 = __low2float(P3), s3 = __high2float(P3);         \
        float c0 = __low2float(P0), s0 = __high2float(P0);         \
        float t3 = s3 * hi[3], u3 = s3 * lo[3];                    \
        float l3 = fmaf(c3, lo[3], -t3);                           \
        float h3 = fmaf(c3, hi[3], u3);                            \
        float t0 = s0 * hi[0], u0 = s0 * lo[0];                    \
        float l0 = fmaf(c0, lo[0], -t0);                           \
        float h0 = fmaf(c0, hi[0], u0);                            \
        float nlo0 = dpp_shr1(l0, l3);                             \
        float nhi3 = dpp_shl1(l3, h0);                             \
        __half2 P1 = f2h2((AA).y), P2 = f2h2((AA).z);              \
        float c1 = __low2float(P1), s1 = __high2float(P1);         \
        float c2 = __low2float(P2), s2 = __high2float(P2);         \
        float t1 = s1 * hi[1], u1 = s1 * lo[1];                    \
        float l1 = fmaf(c1, lo[1], -t1);                           \
        float h1 = fmaf(c1, hi[1], u1);                            \
        float t2 = s2 * hi[2], u2 = s2 * lo[2];                    \
        float l2 = fmaf(c2, lo[2], -t2);                           \
        float h2 = fmaf(c2, hi[2], u2);                            \
        float nlo1 = is0 ? h0 : l0;                                \
        lo[0] = nlo0; lo[1] = nlo1; lo[2] = l1; lo[3] = l2;        \
        hi[0] = h1; hi[1] = h2; hi[2] = h3; hi[3] = nhi3;          \
    }

// Volatile pinned ds_read_b128 with register base + immediate offset.
#define DSRD(dst, addr, imm)                                   \
    asm volatile("ds_read_b128 %0, %1 offset:%c2"              \
                 : "=v"(dst) : "v"(addr), "i"(imm))

// Counted lgkm waits that redefine the covered reg (dataflow ordering).
#define WL3(a) asm volatile("s_waitcnt lgkmcnt(3)" : "+v"(a))
#define WL2(a) asm volatile("s_waitcnt lgkmcnt(2)" : "+v"(a))
#define WL1(a) asm volatile("s_waitcnt lgkmcnt(1)" : "+v"(a))
#define WL0(a) asm volatile("s_waitcnt lgkmcnt(0)" : "+v"(a))

#define WAITV(n) asm volatile("s_waitcnt vmcnt(" #n ")" ::: "memory")
#define BAR()                               \
    __builtin_amdgcn_s_barrier();           \
    __builtin_amdgcn_sched_barrier(0)

// Stage chunk cix (16KB = 16 rounds x 1KB) into buffer bix; wave covers its
// 4KB (4 x 1KB glds16).
#define STAGE(cix, bix)                                              \
    {                                                                \
        const char* g_ = gsrc + (size_t)(cix)*16384;                 \
        char* l_ = lb + (size_t)(bix)*16384;                         \
        _Pragma("unroll")                                            \
        for (int j = 0; j < 4; ++j)                                  \
            glds16(g_ + j * 1024, l_ + j * 1024);                    \
    }

// 16 rounds, rolling 4-round-ahead reads (1 b128/round). Rounds 0..11 read
// same-chunk rounds 4..15 (ACUR); rounds 12..15 read next chunk 0..3 (ANXT).
#define CHUNK16(ACUR, ANXT)                                    \
    WL3(A0); ROUND(A0) DSRD(A0, ACUR,  4 * 1024);              \
    WL3(A1); ROUND(A1) DSRD(A1, ACUR,  5 * 1024);              \
    WL3(A2); ROUND(A2) DSRD(A2, ACUR,  6 * 1024);              \
    WL3(A3); ROUND(A3) DSRD(A3, ACUR,  7 * 1024);              \
    WL3(A0); ROUND(A0) DSRD(A0, ACUR,  8 * 1024);              \
    WL3(A1); ROUND(A1) DSRD(A1, ACUR,  9 * 1024);              \
    WL3(A2); ROUND(A2) DSRD(A2, ACUR, 10 * 1024);              \
    WL3(A3); ROUND(A3) DSRD(A3, ACUR, 11 * 1024);              \
    WL3(A0); ROUND(A0) DSRD(A0, ACUR, 12 * 1024);              \
    WL3(A1); ROUND(A1) DSRD(A1, ACUR, 13 * 1024);              \
    WL3(A2); ROUND(A2) DSRD(A2, ACUR, 14 * 1024);              \
    WL3(A3); ROUND(A3) DSRD(A3, ACUR, 15 * 1024);              \
    WL3(A0); ROUND(A0) DSRD(A0, ANXT,  0 * 1024);              \
    WL3(A1); ROUND(A1) DSRD(A1, ANXT,  1 * 1024);              \
    WL3(A2); ROUND(A2) DSRD(A2, ANXT,  2 * 1024);              \
    WL3(A3); ROUND(A3) DSRD(A3, ANXT,  3 * 1024);

template <bool TAB>
__global__ __launch_bounds__(256, 1) void rotmat_main(const float* __restrict__ x,
                                                      const float* __restrict__ thetas,
                                                      const __half2* __restrict__ cs16,
                                                      float* __restrict__ out) {
    __shared__ f32x4 tab[3 * 1024];  // 3 buffers x 16KB = 48KB

    const int lane = threadIdx.x & 63;
    const int wave = threadIdx.x >> 6;
    const int col  = (blockIdx.x << 2) + wave;  // one column per wave
    const int k0   = lane << 2;                 // first pair index of this lane
    const bool is0 = (lane == 0);

    float lo[4], hi[4];
#pragma unroll
    for (int m = 0; m < 4; ++m) {
        lo[m] = x[(k0 + m) * N_COLS + col];
        hi[m] = x[(511 - k0 - m) * N_COLS + col];
    }

    if constexpr (TAB) {
        const char* gsrc = (const char*)cs16 + (size_t)wave * 4096 + (size_t)lane * 16;
        char* lb = (char*)(&tab[0]) + (size_t)wave * 4096;
        unsigned ldsLane;
        {
            auto p3 = (__attribute__((address_space(3))) char*)(&tab[0]);
            ldsLane = (unsigned)(size_t)p3 + (unsigned)(lane * 16);
        }

        f32x4 A0, A1, A2, A3;  // ring: slot = round mod 4 (each = 4 x half2)

        // Prologue: stage chunks 0,1; both landed; sync; pre-issue reads for
        // chunk 0 rounds 0..3.
        STAGE(0, 0)
        STAGE(1, 1)
        WAITV(0);
        BAR();
        {
            unsigned a0 = ldsLane;  // buffer 0 base
            DSRD(A0, a0, 0 * 1024);
            DSRD(A1, a0, 1 * 1024);
            DSRD(A2, a0, 2 * 1024);
            DSRD(A3, a0, 3 * 1024);
        }

        // Chunks 0..29 (rounds 0..479), staging chunk c+2 each.
        int bufCur = 0, bufNxt = 1, bufStg = 2;
        for (int c = 0; c < 30; ++c) {
            WAITV(0);   // own stage(c+1) landed (issued at top of c-1)
            BAR();      // all waves: stages visible; old-buffer reads retired
            STAGE(c + 2, bufStg)
            unsigned aCur = ldsLane + (unsigned)bufCur * 16384u;
            unsigned aNxt = ldsLane + (unsigned)bufNxt * 16384u;
            CHUNK16(aCur, aNxt)
            int t_ = bufCur; bufCur = bufNxt; bufNxt = bufStg; bufStg = t_;
        }

        // Chunk 30 (rounds 480..495): no staging (chunk 31 staged at c=29).
        {
            WAITV(0);   // stage(31) landed
            BAR();
            unsigned aCur = ldsLane + (unsigned)bufCur * 16384u;
            unsigned aNxt = ldsLane + (unsigned)bufNxt * 16384u;
            CHUNK16(aCur, aNxt)
            int t_ = bufCur; bufCur = bufNxt; bufNxt = bufStg; bufStg = t_;
        }

        // Chunk 31 tail: rounds 496..510 (15 real; pad round 511 never read).
        {
            unsigned aCur = ldsLane + (unsigned)bufCur * 16384u;
            WL3(A0); ROUND(A0) DSRD(A0, aCur,  4 * 1024);
            WL3(A1); ROUND(A1) DSRD(A1, aCur,  5 * 1024);
            WL3(A2); ROUND(A2) DSRD(A2, aCur,  6 * 1024);
            WL3(A3); ROUND(A3) DSRD(A3, aCur,  7 * 1024);
            WL3(A0); ROUND(A0) DSRD(A0, aCur,  8 * 1024);
            WL3(A1); ROUND(A1) DSRD(A1, aCur,  9 * 1024);
            WL3(A2); ROUND(A2) DSRD(A2, aCur, 10 * 1024);
            WL3(A3); ROUND(A3) DSRD(A3, aCur, 11 * 1024);
            WL3(A0); ROUND(A0) DSRD(A0, aCur, 12 * 1024);
            WL3(A1); ROUND(A1) DSRD(A1, aCur, 13 * 1024);
            WL3(A2); ROUND(A2) DSRD(A2, aCur, 14 * 1024);
            WL3(A3); ROUND(A3)   // round 507 (no more issues)
            WL2(A0); ROUND(A0)   // round 508
            WL1(A1); ROUND(A1)   // round 509
            WL0(A2); ROUND(A2)   // round 510; ring drained
        }
    } else {
        // Fallback: compute schedule + sincos inline (no workspace table).
        int pu[4], pv[4];
#pragma unroll
        for (int m = 0; m < 4; ++m) {
            pu[m] = (k0 + m == 0) ? 0 : (k0 + m);
            pv[m] = 511 - (k0 + m);
        }
        for (int r = 0; r < 511; ++r) {
            float cc[4], ss[4];
#pragma unroll
            for (int m = 0; m < 4; ++m) {
                int i = min(pu[m], pv[m]), j = max(pu[m], pv[m]);
                int t = i * 511 - (i * (i - 1)) / 2 + (j - i - 1);
                float s, c;
                sincosf(thetas[t], &s, &c);
                cc[m] = c;
                ss[m] = (pu[m] < pv[m]) ? s : -s;
            }
            {
                float t3 = ss[3] * hi[3], u3 = ss[3] * lo[3];
                float l3 = fmaf(cc[3], lo[3], -t3);
                float h3 = fmaf(cc[3], hi[3], u3);
                float t0 = ss[0] * hi[0], u0 = ss[0] * lo[0];
                float l0 = fmaf(cc[0], lo[0], -t0);
                float h0 = fmaf(cc[0], hi[0], u0);
                float nlo0 = dpp_shr1(l0, l3);
                float nhi3 = dpp_shl1(l3, h0);
                float t1 = ss[1] * hi[1], u1 = ss[1] * lo[1];
                float l1 = fmaf(cc[1], lo[1], -t1);
                float h1 = fmaf(cc[1], hi[1], u1);
                float t2 = ss[2] * hi[2], u2 = ss[2] * lo[2];
                float l2 = fmaf(cc[2], lo[2], -t2);
                float h2 = fmaf(cc[2], hi[2], u2);
                float nlo1 = is0 ? h0 : l0;
                lo[0] = nlo0; lo[1] = nlo1; lo[2] = l1; lo[3] = l2;
                hi[0] = h1; hi[1] = h2; hi[2] = h3; hi[3] = nhi3;
            }
#pragma unroll
            for (int m = 0; m < 4; ++m) {
                pu[m] = (k0 + m == 0) ? 0 : ((pu[m] == 1) ? 511 : pu[m] - 1);
                pv[m] = (pv[m] == 1) ? 511 : pv[m] - 1;
            }
        }
    }

    // After 511 shifts the position->row permutation is identity.
#pragma unroll
    for (int m = 0; m < 4; ++m) {
        out[(k0 + m) * N_COLS + col]       = lo[m];
        out[(511 - k0 - m) * N_COLS + col] = hi[m];
    }
}

extern "C" void kernel_launch(void* const* d_in, const int* in_sizes, int n_in,
                              void* d_out, int out_size, void* d_ws, size_t ws_size,
                              hipStream_t stream) {
    const float* x  = (const float*)d_in[0];
    const float* th = (const float*)d_in[1];
    float* out      = (float*)d_out;

    // Table: 512 rounds x 1KB (round 511 = pad; staged, never consumed).
    const size_t need = (size_t)512 * 1024;  // 512 KiB
    if (ws_size >= need) {
        __half2* cs16 = (__half2*)d_ws;
        rotmat_setup<<<511, PAIRS, 0, stream>>>(th, cs16);
        rotmat_main<true><<<N_COLS / 4, 256, 0, stream>>>(x, th, cs16, out);
    } else {
        rotmat_main<false><<<N_COLS / 4, 256, 0, stream>>>(x, th, nullptr, out);
    }
}